// Round 9
// baseline (287.029 us; speedup 1.0000x reference)
//
#include <hip/hip_runtime.h>
#include <hip/hip_bf16.h>

// Problem constants (from the reference)
#define N_IN_SZ   (721 * 1440)   // 1,038,240
#define N_ROWS    (361 * 720)    //   259,920 output cells
#define BC        64             // B*C = 4*16
#define ROW_CAP   16             // padded entries per row (lambda=4.03)
#define OF_CAP    4096

__device__ __forceinline__ unsigned pack_bf16(float a, float b) {
    __hip_bfloat16 ha = __float2bfloat16(a), hb = __float2bfloat16(b);
    unsigned short ua = *(unsigned short*)&ha, ub = *(unsigned short*)&hb;
    return (unsigned)ua | ((unsigned)ub << 16);
}

// ---------------- fused prep: scatter (every 5th block) || reg-transpose ----------------
// transpose: thread owns column c; 64 coalesced 4B loads (256B/wave-instr),
// pack 32 uints (bc-pairs as bf16x2), write 8 x uint4 = the 128B xt row.
// No LDS, no syncthreads, 16 loads in flight per thread.

__global__ void prep_kernel(const float* __restrict__ x,
                            const int* __restrict__ rows, const int* __restrict__ cols,
                            const float* __restrict__ S,
                            int* __restrict__ cursor, int2* __restrict__ epad,
                            int* __restrict__ of_count, int4* __restrict__ of_list,
                            __hip_bfloat16* __restrict__ xt,
                            int nnz) {
    const int bid = blockIdx.x;

    if ((bid % 5) == 4) {
        // ---- scatter part (interleaved through the dispatch) ----
        const int nsc = gridDim.x / 5;
        const int stride = nsc * 256;
        for (int k = (bid / 5) * 256 + threadIdx.x; k < nnz; k += stride) {
            const int r = rows[k];
            const int slot = atomicAdd(&cursor[r], 1);
            if (slot < ROW_CAP) {
                epad[(size_t)r * ROW_CAP + slot] = make_int2(cols[k], __float_as_int(S[k]));
            } else {
                int o = atomicAdd(of_count, 1);
                if (o < OF_CAP) of_list[o] = make_int4(r, cols[k], __float_as_int(S[k]), 0);
            }
        }
        return;
    }

    // ---- register transpose part ----
    const int t_idx = bid - bid / 5;               // 0 .. 4055
    const int c = t_idx * 256 + threadIdx.x;       // column this thread owns
    if (c >= N_IN_SZ) return;
    const float* __restrict__ xc = x + c;

    uint4 orow[2];   // per-chunk output (8 uints = 16 bc)
    unsigned* ou = (unsigned*)orow;
    #pragma unroll
    for (int ch = 0; ch < 4; ++ch) {
        float v[16];
        #pragma unroll
        for (int i = 0; i < 16; ++i)
            v[i] = xc[(size_t)(ch * 16 + i) * N_IN_SZ];   // 16 independent loads
        #pragma unroll
        for (int p = 0; p < 8; ++p)
            ou[p] = pack_bf16(v[2 * p], v[2 * p + 1]);
        uint4* dst = (uint4*)(xt + (size_t)c * 64 + ch * 16);
        dst[0] = orow[0];
        dst[1] = orow[1];
    }
}

// ---------------- gather: block = 64 rows x 64 bc; wave owns 16 rows, ----------------
// processed as pairs (rr, rr+8) with batch-4 UNCONDITIONAL loads -> ~8 loads in flight.
// Register accumulation (no LDS atomics), LDS tile + coalesced float4 writeout.

__global__ void gather_kernel(const __hip_bfloat16* __restrict__ xt,
                              const int* __restrict__ cursor,
                              const int2* __restrict__ epad,
                              float* __restrict__ y) {
    __shared__ float tile[64][65];
    __shared__ int cnt[64];
    const int b = blockIdx.x;
    const int base = b * 64;
    const int lane = threadIdx.x & 63;
    const int wave = threadIdx.x >> 6;

    if (threadIdx.x < 64) {
        const int r = base + threadIdx.x;
        int cc = (r < N_ROWS) ? cursor[r] : 0;
        cnt[threadIdx.x] = (cc > ROW_CAP) ? ROW_CAP : cc;
    }
    __syncthreads();

    for (int rr = 0; rr < 8; ++rr) {
        const int r0 = wave * 16 + rr;
        const int r1 = r0 + 8;
        const int c0 = cnt[r0];
        const int c1 = cnt[r1];
        const int2* __restrict__ e0 = epad + (size_t)(base + r0) * ROW_CAP;
        const int2* __restrict__ e1 = epad + (size_t)(base + r1) * ROW_CAP;
        float a0 = 0.f, a1 = 0.f;
        int t0 = 0, t1 = 0;
        while (t0 < c0 || t1 < c1) {
            const bool g0 = (t0 < c0), g1 = (t1 < c1);
            int2 E0[4], E1[4];
            #pragma unroll
            for (int j = 0; j < 4; ++j) E0[j] = g0 ? e0[t0 + j] : make_int2(0, 0);
            #pragma unroll
            for (int j = 0; j < 4; ++j) E1[j] = g1 ? e1[t1 + j] : make_int2(0, 0);
            float x0[4], x1[4];
            #pragma unroll
            for (int j = 0; j < 4; ++j) {
                const int col = (t0 + j < c0) ? E0[j].x : 0;
                x0[j] = __bfloat162float(xt[(size_t)col * 64 + lane]);
            }
            #pragma unroll
            for (int j = 0; j < 4; ++j) {
                const int col = (t1 + j < c1) ? E1[j].x : 0;
                x1[j] = __bfloat162float(xt[(size_t)col * 64 + lane]);
            }
            #pragma unroll
            for (int j = 0; j < 4; ++j) {
                const float w0 = (t0 + j < c0) ? __int_as_float(E0[j].y) : 0.f;
                a0 += w0 * x0[j];
            }
            #pragma unroll
            for (int j = 0; j < 4; ++j) {
                const float w1 = (t1 + j < c1) ? __int_as_float(E1[j].y) : 0.f;
                a1 += w1 * x1[j];
            }
            if (g0) t0 += 4;
            if (g1) t1 += 4;
        }
        tile[lane][r0] = a0;
        tile[lane][r1] = a1;
    }
    __syncthreads();

    // writeout: 1024 float4 tasks = 64 bc x 16 quads; 4 per thread
    #pragma unroll
    for (int j = 0; j < 4; ++j) {
        const int task = j * 256 + threadIdx.x;
        const int bc = task >> 4;
        const int r0 = (task & 15) * 4;
        const int i0 = base + r0;
        float4 v = make_float4(tile[bc][r0], tile[bc][r0 + 1],
                               tile[bc][r0 + 2], tile[bc][r0 + 3]);
        float* yp = y + (size_t)bc * N_ROWS;
        if (i0 + 3 < N_ROWS) {
            *(float4*)&yp[i0] = v;
        } else {
            if (i0 + 0 < N_ROWS) yp[i0 + 0] = v.x;
            if (i0 + 1 < N_ROWS) yp[i0 + 1] = v.y;
            if (i0 + 2 < N_ROWS) yp[i0 + 2] = v.z;
            if (i0 + 3 < N_ROWS) yp[i0 + 3] = v.w;
        }
    }
}

// ---------------- overflow cleanup (expected ~0 entries) ----------------

__global__ void cleanup_kernel(const int* __restrict__ of_count,
                               const int4* __restrict__ of_list,
                               const float* __restrict__ x, float* __restrict__ y) {
    int n = *of_count;
    if (n > OF_CAP) n = OF_CAP;
    const int total = n * 64;
    for (int t = blockIdx.x * blockDim.x + threadIdx.x; t < total;
         t += gridDim.x * blockDim.x) {
        const int e = t >> 6, bc = t & 63;
        const int4 E = of_list[e];
        atomicAdd(&y[(size_t)bc * N_ROWS + E.x],
                  __int_as_float(E.z) * x[(size_t)bc * N_IN_SZ + E.y]);
    }
}

// ---------------- last-resort atomic COO ----------------

__global__ void regrid_coo_kernel(const float* __restrict__ x, const float* __restrict__ S,
                                  const int* __restrict__ rows, const int* __restrict__ cols,
                                  float* __restrict__ y, int nnz) {
    const int bc = blockIdx.y;
    const float* __restrict__ xp = x + (size_t)bc * N_IN_SZ;
    float* __restrict__ yp = y + (size_t)bc * N_ROWS;
    int k = blockIdx.x * blockDim.x + threadIdx.x;
    const int stride = gridDim.x * blockDim.x;
    for (; k < nnz; k += stride) {
        atomicAdd(&yp[rows[k]], S[k] * xp[cols[k]]);
    }
}

extern "C" void kernel_launch(void* const* d_in, const int* in_sizes, int n_in,
                              void* d_out, int out_size, void* d_ws, size_t ws_size,
                              hipStream_t stream) {
    const float* x    = (const float*)d_in[0];
    const float* S    = (const float*)d_in[1];
    const int*   rows = (const int*)d_in[2];
    const int*   cols = (const int*)d_in[3];
    float*       y    = (float*)d_out;
    const int nnz = in_sizes[1];

    // Workspace layout (256B-aligned chunks)
    const size_t SZ_CURSOR = ((size_t)N_ROWS * 4 + 255) & ~255ULL;             // 1.04 MB
    const size_t SZ_OFCNT  = 256;
    const size_t SZ_OFLIST = ((size_t)OF_CAP * 16 + 255) & ~255ULL;            // 64 KB
    const size_t SZ_EPAD   = ((size_t)N_ROWS * ROW_CAP * 8 + 255) & ~255ULL;   // 33.3 MB
    const size_t SZ_XT     = ((size_t)N_IN_SZ * BC * 2 + 255) & ~255ULL;       // 133 MB
    const size_t NEED = SZ_CURSOR + SZ_OFCNT + SZ_OFLIST + SZ_EPAD + SZ_XT;

    if (ws_size < NEED) {
        hipMemsetAsync(d_out, 0, (size_t)out_size * sizeof(float), stream);
        dim3 grid(1024, BC, 1);
        regrid_coo_kernel<<<grid, 256, 0, stream>>>(x, S, rows, cols, y, nnz);
        return;
    }

    char* w = (char*)d_ws;
    int*  cursor   = (int*)(w);
    int*  of_count = (int*)(w + SZ_CURSOR);
    int4* of_list  = (int4*)(w + SZ_CURSOR + SZ_OFCNT);
    int2* epad     = (int2*)(w + SZ_CURSOR + SZ_OFCNT + SZ_OFLIST);
    __hip_bfloat16* xt = (__hip_bfloat16*)(w + SZ_CURSOR + SZ_OFCNT + SZ_OFLIST + SZ_EPAD);

    // zero cursors + overflow count in one memset (contiguous)
    hipMemsetAsync(cursor, 0, SZ_CURSOR + SZ_OFCNT, stream);

    // 4056 transpose blocks (256 cols each) + 1014 scatter blocks, interleaved 1:5
    const int tBlocks = (N_IN_SZ + 255) / 256;        // 4056
    const int nsc     = (tBlocks + 3) / 4;            // 1014
    const int nGrid   = 5 * nsc;                      // 5070 (transpose slots = 4056)
    prep_kernel<<<nGrid, 256, 0, stream>>>(x, rows, cols, S, cursor, epad,
                                           of_count, of_list, xt, nnz);

    const int gBlocks = (N_ROWS + 63) / 64;           // 4,062
    gather_kernel<<<gBlocks, 256, 0, stream>>>(xt, cursor, epad, y);

    cleanup_kernel<<<16, 256, 0, stream>>>(of_count, of_list, x, y);
}

// Round 10
// 286.153 us; speedup vs baseline: 1.0031x; 1.0031x over previous
//
#include <hip/hip_runtime.h>
#include <hip/hip_bf16.h>

// Problem constants (from the reference)
#define N_IN_SZ   (721 * 1440)   // 1,038,240
#define N_ROWS    (361 * 720)    //   259,920 output cells
#define BC        64             // B*C = 4*16
#define ROW_CAP   16             // padded entries per row (lambda=4.03)
#define OF_CAP    4096

__device__ __forceinline__ unsigned pack_bf16(float a, float b) {
    __hip_bfloat16 ha = __float2bfloat16(a), hb = __float2bfloat16(b);
    unsigned short ua = *(unsigned short*)&ha, ub = *(unsigned short*)&hb;
    return (unsigned)ua | ((unsigned)ub << 16);
}

// ---------------- fused prep: scatter (every 5th block) || reg-transpose ----------------
// transpose: thread owns column c; per HALF: 32 coalesced 4B loads (32 in flight),
// pack 16 uints (bc-pairs as bf16x2) = exactly one 64B xt line, store as 4 uint4
// back-to-back -> every line completes within a ~4-instr window (clean L2 combine).
// No LDS, no syncthreads.

__global__ void prep_kernel(const float* __restrict__ x,
                            const int* __restrict__ rows, const int* __restrict__ cols,
                            const float* __restrict__ S,
                            int* __restrict__ cursor, int2* __restrict__ epad,
                            int* __restrict__ of_count, int4* __restrict__ of_list,
                            __hip_bfloat16* __restrict__ xt,
                            int nnz) {
    const int bid = blockIdx.x;

    if ((bid % 5) == 4) {
        // ---- scatter part (interleaved through the dispatch) ----
        const int nsc = gridDim.x / 5;
        const int stride = nsc * 256;
        for (int k = (bid / 5) * 256 + threadIdx.x; k < nnz; k += stride) {
            const int r = rows[k];
            const int slot = atomicAdd(&cursor[r], 1);
            if (slot < ROW_CAP) {
                epad[(size_t)r * ROW_CAP + slot] = make_int2(cols[k], __float_as_int(S[k]));
            } else {
                int o = atomicAdd(of_count, 1);
                if (o < OF_CAP) of_list[o] = make_int4(r, cols[k], __float_as_int(S[k]), 0);
            }
        }
        return;
    }

    // ---- register transpose part ----
    const int t_idx = bid - bid / 5;               // 0 .. 4055
    const int c = t_idx * 256 + threadIdx.x;       // column this thread owns
    if (c >= N_IN_SZ) return;
    const float* __restrict__ xc = x + c;

    #pragma unroll
    for (int half = 0; half < 2; ++half) {
        float v[32];
        #pragma unroll
        for (int i = 0; i < 32; ++i)
            v[i] = xc[(size_t)(half * 32 + i) * N_IN_SZ];   // 32 independent loads
        unsigned u[16];
        #pragma unroll
        for (int p = 0; p < 16; ++p)
            u[p] = pack_bf16(v[2 * p], v[2 * p + 1]);
        uint4* dst = (uint4*)(xt + (size_t)c * 64 + half * 32);  // one 64B line
        dst[0] = ((uint4*)u)[0];
        dst[1] = ((uint4*)u)[1];
        dst[2] = ((uint4*)u)[2];
        dst[3] = ((uint4*)u)[3];
    }
}

// ---------------- gather: block = 64 rows x 64 bc; wave owns 16 rows, ----------------
// processed as pairs (rr, rr+8) with batch-4 UNCONDITIONAL loads -> ~8 loads in flight.
// Register accumulation (no LDS atomics), LDS tile + coalesced float4 writeout.

__global__ void gather_kernel(const __hip_bfloat16* __restrict__ xt,
                              const int* __restrict__ cursor,
                              const int2* __restrict__ epad,
                              float* __restrict__ y) {
    __shared__ float tile[64][65];
    __shared__ int cnt[64];
    const int b = blockIdx.x;
    const int base = b * 64;
    const int lane = threadIdx.x & 63;
    const int wave = threadIdx.x >> 6;

    if (threadIdx.x < 64) {
        const int r = base + threadIdx.x;
        int cc = (r < N_ROWS) ? cursor[r] : 0;
        cnt[threadIdx.x] = (cc > ROW_CAP) ? ROW_CAP : cc;
    }
    __syncthreads();

    for (int rr = 0; rr < 8; ++rr) {
        const int r0 = wave * 16 + rr;
        const int r1 = r0 + 8;
        const int c0 = cnt[r0];
        const int c1 = cnt[r1];
        const int2* __restrict__ e0 = epad + (size_t)(base + r0) * ROW_CAP;
        const int2* __restrict__ e1 = epad + (size_t)(base + r1) * ROW_CAP;
        float a0 = 0.f, a1 = 0.f;
        int t0 = 0, t1 = 0;
        while (t0 < c0 || t1 < c1) {
            const bool g0 = (t0 < c0), g1 = (t1 < c1);
            int2 E0[4], E1[4];
            #pragma unroll
            for (int j = 0; j < 4; ++j) E0[j] = g0 ? e0[t0 + j] : make_int2(0, 0);
            #pragma unroll
            for (int j = 0; j < 4; ++j) E1[j] = g1 ? e1[t1 + j] : make_int2(0, 0);
            float x0[4], x1[4];
            #pragma unroll
            for (int j = 0; j < 4; ++j) {
                const int col = (t0 + j < c0) ? E0[j].x : 0;
                x0[j] = __bfloat162float(xt[(size_t)col * 64 + lane]);
            }
            #pragma unroll
            for (int j = 0; j < 4; ++j) {
                const int col = (t1 + j < c1) ? E1[j].x : 0;
                x1[j] = __bfloat162float(xt[(size_t)col * 64 + lane]);
            }
            #pragma unroll
            for (int j = 0; j < 4; ++j) {
                const float w0 = (t0 + j < c0) ? __int_as_float(E0[j].y) : 0.f;
                a0 += w0 * x0[j];
            }
            #pragma unroll
            for (int j = 0; j < 4; ++j) {
                const float w1 = (t1 + j < c1) ? __int_as_float(E1[j].y) : 0.f;
                a1 += w1 * x1[j];
            }
            if (g0) t0 += 4;
            if (g1) t1 += 4;
        }
        tile[lane][r0] = a0;
        tile[lane][r1] = a1;
    }
    __syncthreads();

    // writeout: 1024 float4 tasks = 64 bc x 16 quads; 4 per thread
    #pragma unroll
    for (int j = 0; j < 4; ++j) {
        const int task = j * 256 + threadIdx.x;
        const int bc = task >> 4;
        const int r0 = (task & 15) * 4;
        const int i0 = base + r0;
        float4 v = make_float4(tile[bc][r0], tile[bc][r0 + 1],
                               tile[bc][r0 + 2], tile[bc][r0 + 3]);
        float* yp = y + (size_t)bc * N_ROWS;
        if (i0 + 3 < N_ROWS) {
            *(float4*)&yp[i0] = v;
        } else {
            if (i0 + 0 < N_ROWS) yp[i0 + 0] = v.x;
            if (i0 + 1 < N_ROWS) yp[i0 + 1] = v.y;
            if (i0 + 2 < N_ROWS) yp[i0 + 2] = v.z;
            if (i0 + 3 < N_ROWS) yp[i0 + 3] = v.w;
        }
    }
}

// ---------------- overflow cleanup (expected ~0 entries) ----------------

__global__ void cleanup_kernel(const int* __restrict__ of_count,
                               const int4* __restrict__ of_list,
                               const float* __restrict__ x, float* __restrict__ y) {
    int n = *of_count;
    if (n > OF_CAP) n = OF_CAP;
    const int total = n * 64;
    for (int t = blockIdx.x * blockDim.x + threadIdx.x; t < total;
         t += gridDim.x * blockDim.x) {
        const int e = t >> 6, bc = t & 63;
        const int4 E = of_list[e];
        atomicAdd(&y[(size_t)bc * N_ROWS + E.x],
                  __int_as_float(E.z) * x[(size_t)bc * N_IN_SZ + E.y]);
    }
}

// ---------------- last-resort atomic COO ----------------

__global__ void regrid_coo_kernel(const float* __restrict__ x, const float* __restrict__ S,
                                  const int* __restrict__ rows, const int* __restrict__ cols,
                                  float* __restrict__ y, int nnz) {
    const int bc = blockIdx.y;
    const float* __restrict__ xp = x + (size_t)bc * N_IN_SZ;
    float* __restrict__ yp = y + (size_t)bc * N_ROWS;
    int k = blockIdx.x * blockDim.x + threadIdx.x;
    const int stride = gridDim.x * blockDim.x;
    for (; k < nnz; k += stride) {
        atomicAdd(&yp[rows[k]], S[k] * xp[cols[k]]);
    }
}

extern "C" void kernel_launch(void* const* d_in, const int* in_sizes, int n_in,
                              void* d_out, int out_size, void* d_ws, size_t ws_size,
                              hipStream_t stream) {
    const float* x    = (const float*)d_in[0];
    const float* S    = (const float*)d_in[1];
    const int*   rows = (const int*)d_in[2];
    const int*   cols = (const int*)d_in[3];
    float*       y    = (float*)d_out;
    const int nnz = in_sizes[1];

    // Workspace layout (256B-aligned chunks)
    const size_t SZ_CURSOR = ((size_t)N_ROWS * 4 + 255) & ~255ULL;             // 1.04 MB
    const size_t SZ_OFCNT  = 256;
    const size_t SZ_OFLIST = ((size_t)OF_CAP * 16 + 255) & ~255ULL;            // 64 KB
    const size_t SZ_EPAD   = ((size_t)N_ROWS * ROW_CAP * 8 + 255) & ~255ULL;   // 33.3 MB
    const size_t SZ_XT     = ((size_t)N_IN_SZ * BC * 2 + 255) & ~255ULL;       // 133 MB
    const size_t NEED = SZ_CURSOR + SZ_OFCNT + SZ_OFLIST + SZ_EPAD + SZ_XT;

    if (ws_size < NEED) {
        hipMemsetAsync(d_out, 0, (size_t)out_size * sizeof(float), stream);
        dim3 grid(1024, BC, 1);
        regrid_coo_kernel<<<grid, 256, 0, stream>>>(x, S, rows, cols, y, nnz);
        return;
    }

    char* w = (char*)d_ws;
    int*  cursor   = (int*)(w);
    int*  of_count = (int*)(w + SZ_CURSOR);
    int4* of_list  = (int4*)(w + SZ_CURSOR + SZ_OFCNT);
    int2* epad     = (int2*)(w + SZ_CURSOR + SZ_OFCNT + SZ_OFLIST);
    __hip_bfloat16* xt = (__hip_bfloat16*)(w + SZ_CURSOR + SZ_OFCNT + SZ_OFLIST + SZ_EPAD);

    // zero cursors + overflow count in one memset (contiguous)
    hipMemsetAsync(cursor, 0, SZ_CURSOR + SZ_OFCNT, stream);

    // 4056 transpose blocks (256 cols each) + 1014 scatter blocks, interleaved 1:5
    const int tBlocks = (N_IN_SZ + 255) / 256;        // 4056
    const int nsc     = (tBlocks + 3) / 4;            // 1014
    const int nGrid   = 5 * nsc;                      // 5070 (transpose slots = 4056)
    prep_kernel<<<nGrid, 256, 0, stream>>>(x, rows, cols, S, cursor, epad,
                                           of_count, of_list, xt, nnz);

    const int gBlocks = (N_ROWS + 63) / 64;           // 4,062
    gather_kernel<<<gBlocks, 256, 0, stream>>>(xt, cursor, epad, y);

    cleanup_kernel<<<16, 256, 0, stream>>>(of_count, of_list, x, y);
}

// Round 11
// 246.583 us; speedup vs baseline: 1.1640x; 1.1605x over previous
//
#include <hip/hip_runtime.h>
#include <hip/hip_bf16.h>

// Problem constants (from the reference)
#define N_IN_SZ   (721 * 1440)   // 1,038,240  (divisible by 16; x4B rows are 64B-aligned)
#define N_ROWS    (361 * 720)    //   259,920 output cells
#define BC        64             // B*C = 4*16
#define ROW_CAP   16             // padded entries per row (lambda=4.03)
#define OF_CAP    4096

// ---------------- fused prep: scatter (every 5th block) || reg-transpose ----------------
// transpose: lane = bc, wave owns 16 cols. Lane loads 4 x float4 from ONE 64B x-line
// (scattered across lanes -> MSHR-merged reads); stores are wave-contiguous 128B xt
// rows (ushort per lane) -> zero partial-line writes. No LDS, no syncthreads.

__global__ void prep_kernel(const float* __restrict__ x,
                            const int* __restrict__ rows, const int* __restrict__ cols,
                            const float* __restrict__ S,
                            int* __restrict__ cursor, int2* __restrict__ epad,
                            int* __restrict__ of_count, int4* __restrict__ of_list,
                            __hip_bfloat16* __restrict__ xt,
                            int nnz) {
    const int bid = blockIdx.x;

    if ((bid % 5) == 4) {
        // ---- scatter part (interleaved through the dispatch) ----
        const int nsc = gridDim.x / 5;
        const int stride = nsc * 256;
        for (int k = (bid / 5) * 256 + threadIdx.x; k < nnz; k += stride) {
            const int r = rows[k];
            const int slot = atomicAdd(&cursor[r], 1);
            if (slot < ROW_CAP) {
                epad[(size_t)r * ROW_CAP + slot] = make_int2(cols[k], __float_as_int(S[k]));
            } else {
                int o = atomicAdd(of_count, 1);
                if (o < OF_CAP) of_list[o] = make_int4(r, cols[k], __float_as_int(S[k]), 0);
            }
        }
        return;
    }

    // ---- register transpose: block covers 64 cols (4 waves x 16 cols), lane = bc ----
    const int t_idx = bid - bid / 5;                       // 0 .. 16222
    const int lane = threadIdx.x & 63;                     // bc
    const int wave = threadIdx.x >> 6;                     // 0..3
    const int c_base = t_idx * 64 + wave * 16;             // 16-col window = one x line
    if (c_base >= N_IN_SZ) return;                         // tail block: waves 2,3 idle

    const float* __restrict__ xp = x + (size_t)lane * N_IN_SZ + c_base;
    float4 v0 = *(const float4*)(xp + 0);
    float4 v1 = *(const float4*)(xp + 4);
    float4 v2 = *(const float4*)(xp + 8);
    float4 v3 = *(const float4*)(xp + 12);

    const float vf[16] = {v0.x, v0.y, v0.z, v0.w, v1.x, v1.y, v1.z, v1.w,
                          v2.x, v2.y, v2.z, v2.w, v3.x, v3.y, v3.z, v3.w};
    #pragma unroll
    for (int j = 0; j < 16; ++j) {
        __hip_bfloat16 h = __float2bfloat16(vf[j]);
        // 64 lanes write 2B each -> one contiguous 128B xt row per instruction
        *(unsigned short*)&xt[(size_t)(c_base + j) * 64 + lane] = *(unsigned short*)&h;
    }
}

// ---------------- gather: block = 64 rows x 64 bc; wave owns 16 rows, ----------------
// processed as pairs (rr, rr+8) with batch-4 UNCONDITIONAL loads -> ~8 loads in flight.
// Register accumulation (no LDS atomics), LDS tile + coalesced float4 writeout.

__global__ void gather_kernel(const __hip_bfloat16* __restrict__ xt,
                              const int* __restrict__ cursor,
                              const int2* __restrict__ epad,
                              float* __restrict__ y) {
    __shared__ float tile[64][65];
    __shared__ int cnt[64];
    const int b = blockIdx.x;
    const int base = b * 64;
    const int lane = threadIdx.x & 63;
    const int wave = threadIdx.x >> 6;

    if (threadIdx.x < 64) {
        const int r = base + threadIdx.x;
        int cc = (r < N_ROWS) ? cursor[r] : 0;
        cnt[threadIdx.x] = (cc > ROW_CAP) ? ROW_CAP : cc;
    }
    __syncthreads();

    for (int rr = 0; rr < 8; ++rr) {
        const int r0 = wave * 16 + rr;
        const int r1 = r0 + 8;
        const int c0 = cnt[r0];
        const int c1 = cnt[r1];
        const int2* __restrict__ e0 = epad + (size_t)(base + r0) * ROW_CAP;
        const int2* __restrict__ e1 = epad + (size_t)(base + r1) * ROW_CAP;
        float a0 = 0.f, a1 = 0.f;
        int t0 = 0, t1 = 0;
        while (t0 < c0 || t1 < c1) {
            const bool g0 = (t0 < c0), g1 = (t1 < c1);
            int2 E0[4], E1[4];
            #pragma unroll
            for (int j = 0; j < 4; ++j) E0[j] = g0 ? e0[t0 + j] : make_int2(0, 0);
            #pragma unroll
            for (int j = 0; j < 4; ++j) E1[j] = g1 ? e1[t1 + j] : make_int2(0, 0);
            float x0[4], x1[4];
            #pragma unroll
            for (int j = 0; j < 4; ++j) {
                const int col = (t0 + j < c0) ? E0[j].x : 0;
                x0[j] = __bfloat162float(xt[(size_t)col * 64 + lane]);
            }
            #pragma unroll
            for (int j = 0; j < 4; ++j) {
                const int col = (t1 + j < c1) ? E1[j].x : 0;
                x1[j] = __bfloat162float(xt[(size_t)col * 64 + lane]);
            }
            #pragma unroll
            for (int j = 0; j < 4; ++j) {
                const float w0 = (t0 + j < c0) ? __int_as_float(E0[j].y) : 0.f;
                a0 += w0 * x0[j];
            }
            #pragma unroll
            for (int j = 0; j < 4; ++j) {
                const float w1 = (t1 + j < c1) ? __int_as_float(E1[j].y) : 0.f;
                a1 += w1 * x1[j];
            }
            if (g0) t0 += 4;
            if (g1) t1 += 4;
        }
        tile[lane][r0] = a0;
        tile[lane][r1] = a1;
    }
    __syncthreads();

    // writeout: 1024 float4 tasks = 64 bc x 16 quads; 4 per thread
    #pragma unroll
    for (int j = 0; j < 4; ++j) {
        const int task = j * 256 + threadIdx.x;
        const int bc = task >> 4;
        const int r0 = (task & 15) * 4;
        const int i0 = base + r0;
        float4 v = make_float4(tile[bc][r0], tile[bc][r0 + 1],
                               tile[bc][r0 + 2], tile[bc][r0 + 3]);
        float* yp = y + (size_t)bc * N_ROWS;
        if (i0 + 3 < N_ROWS) {
            *(float4*)&yp[i0] = v;
        } else {
            if (i0 + 0 < N_ROWS) yp[i0 + 0] = v.x;
            if (i0 + 1 < N_ROWS) yp[i0 + 1] = v.y;
            if (i0 + 2 < N_ROWS) yp[i0 + 2] = v.z;
            if (i0 + 3 < N_ROWS) yp[i0 + 3] = v.w;
        }
    }
}

// ---------------- overflow cleanup (expected ~0 entries) ----------------

__global__ void cleanup_kernel(const int* __restrict__ of_count,
                               const int4* __restrict__ of_list,
                               const float* __restrict__ x, float* __restrict__ y) {
    int n = *of_count;
    if (n > OF_CAP) n = OF_CAP;
    const int total = n * 64;
    for (int t = blockIdx.x * blockDim.x + threadIdx.x; t < total;
         t += gridDim.x * blockDim.x) {
        const int e = t >> 6, bc = t & 63;
        const int4 E = of_list[e];
        atomicAdd(&y[(size_t)bc * N_ROWS + E.x],
                  __int_as_float(E.z) * x[(size_t)bc * N_IN_SZ + E.y]);
    }
}

// ---------------- last-resort atomic COO ----------------

__global__ void regrid_coo_kernel(const float* __restrict__ x, const float* __restrict__ S,
                                  const int* __restrict__ rows, const int* __restrict__ cols,
                                  float* __restrict__ y, int nnz) {
    const int bc = blockIdx.y;
    const float* __restrict__ xp = x + (size_t)bc * N_IN_SZ;
    float* __restrict__ yp = y + (size_t)bc * N_ROWS;
    int k = blockIdx.x * blockDim.x + threadIdx.x;
    const int stride = gridDim.x * blockDim.x;
    for (; k < nnz; k += stride) {
        atomicAdd(&yp[rows[k]], S[k] * xp[cols[k]]);
    }
}

extern "C" void kernel_launch(void* const* d_in, const int* in_sizes, int n_in,
                              void* d_out, int out_size, void* d_ws, size_t ws_size,
                              hipStream_t stream) {
    const float* x    = (const float*)d_in[0];
    const float* S    = (const float*)d_in[1];
    const int*   rows = (const int*)d_in[2];
    const int*   cols = (const int*)d_in[3];
    float*       y    = (float*)d_out;
    const int nnz = in_sizes[1];

    // Workspace layout (256B-aligned chunks)
    const size_t SZ_CURSOR = ((size_t)N_ROWS * 4 + 255) & ~255ULL;             // 1.04 MB
    const size_t SZ_OFCNT  = 256;
    const size_t SZ_OFLIST = ((size_t)OF_CAP * 16 + 255) & ~255ULL;            // 64 KB
    const size_t SZ_EPAD   = ((size_t)N_ROWS * ROW_CAP * 8 + 255) & ~255ULL;   // 33.3 MB
    const size_t SZ_XT     = ((size_t)N_IN_SZ * BC * 2 + 255) & ~255ULL;       // 133 MB
    const size_t NEED = SZ_CURSOR + SZ_OFCNT + SZ_OFLIST + SZ_EPAD + SZ_XT;

    if (ws_size < NEED) {
        hipMemsetAsync(d_out, 0, (size_t)out_size * sizeof(float), stream);
        dim3 grid(1024, BC, 1);
        regrid_coo_kernel<<<grid, 256, 0, stream>>>(x, S, rows, cols, y, nnz);
        return;
    }

    char* w = (char*)d_ws;
    int*  cursor   = (int*)(w);
    int*  of_count = (int*)(w + SZ_CURSOR);
    int4* of_list  = (int4*)(w + SZ_CURSOR + SZ_OFCNT);
    int2* epad     = (int2*)(w + SZ_CURSOR + SZ_OFCNT + SZ_OFLIST);
    __hip_bfloat16* xt = (__hip_bfloat16*)(w + SZ_CURSOR + SZ_OFCNT + SZ_OFLIST + SZ_EPAD);

    // zero cursors + overflow count in one memset (contiguous)
    hipMemsetAsync(cursor, 0, SZ_CURSOR + SZ_OFCNT, stream);

    // 16,223 transpose blocks (64 cols each) + ~4056 scatter blocks, interleaved 1:5
    const int tBlocks = (N_IN_SZ + 63) / 64;          // 16,223
    const int nsc     = (tBlocks + 3) / 4;            // 4,056
    const int nGrid   = 5 * nsc;                      // 20,280 (transpose slots >= 16,223)
    prep_kernel<<<nGrid, 256, 0, stream>>>(x, rows, cols, S, cursor, epad,
                                           of_count, of_list, xt, nnz);

    const int gBlocks = (N_ROWS + 63) / 64;           // 4,062
    gather_kernel<<<gBlocks, 256, 0, stream>>>(xt, cursor, epad, y);

    cleanup_kernel<<<16, 256, 0, stream>>>(of_count, of_list, x, y);
}